// Round 1
// baseline (145.541 us; speedup 1.0000x reference)
//
#include <hip/hip_runtime.h>

#define DIM 256

// One block per node, 256 threads; thread e owns output column e.
// mean(children) staged in LDS; W[s] read coalesced (lane e -> W[s][d][e]).
__global__ __launch_bounds__(256) void level_big(const int* __restrict__ x_sym,
                                                 const float* __restrict__ W,
                                                 const float* __restrict__ b,
                                                 float* __restrict__ enc,
                                                 int lo, int N) {
    const int node = lo + blockIdx.x;
    const int e = threadIdx.x;
    __shared__ float mean_s[DIM];
    const int s = x_sym[node];
    const int c0 = 2 * node + 1;

    float acc = b[s * DIM + e];
    if (c0 < N) {  // block-uniform branch (depends only on blockIdx)
        mean_s[e] = 0.5f * (enc[(size_t)c0 * DIM + e] + enc[(size_t)(c0 + 1) * DIM + e]);
        __syncthreads();
        const float* __restrict__ Ws = W + ((size_t)s << 16);
        #pragma unroll 8
        for (int d = 0; d < DIM; ++d)
            acc = fmaf(mean_s[d], Ws[d * DIM + e], acc);
    }
    enc[(size_t)node * DIM + e] = tanhf(acc);
}

// Small levels: grid = n_nodes * 4; each block handles a 64-column tile of one
// node with a 4-way K split (256 threads = 4 K-chunks x 64 columns), LDS reduce.
__global__ __launch_bounds__(256) void level_small(const int* __restrict__ x_sym,
                                                   const float* __restrict__ W,
                                                   const float* __restrict__ b,
                                                   float* __restrict__ enc,
                                                   int lo, int N) {
    const int node = lo + (blockIdx.x >> 2);
    const int tile = blockIdx.x & 3;          // which 64-column tile
    const int t = threadIdx.x;
    const int kc = t >> 6;                    // K chunk 0..3
    const int lane = t & 63;
    const int c = tile * 64 + lane;           // output column

    __shared__ float mean_s[DIM];
    __shared__ float part[256];

    const int s = x_sym[node];
    const int c0 = 2 * node + 1;

    float m = 0.0f;
    if (c0 < N)
        m = 0.5f * (enc[(size_t)c0 * DIM + t] + enc[(size_t)(c0 + 1) * DIM + t]);
    mean_s[t] = m;
    __syncthreads();

    float acc = 0.0f;
    if (c0 < N) {
        const float* __restrict__ Ws = W + ((size_t)s << 16);
        const int d0 = kc * 64;
        #pragma unroll 8
        for (int d = d0; d < d0 + 64; ++d)
            acc = fmaf(mean_s[d], Ws[d * DIM + c], acc);
    }
    part[t] = acc;
    __syncthreads();

    if (t < 64) {
        float r = part[t] + part[t + 64] + part[t + 128] + part[t + 192];
        r += b[s * DIM + c];
        enc[(size_t)node * DIM + c] = tanhf(r);
    }
}

// Head: out[o] = enc[root] @ W_out[:,o] + b_out[o], OUT=10.
__global__ void out_kernel(const float* __restrict__ enc,
                           const float* __restrict__ W_out,
                           const float* __restrict__ b_out,
                           float* __restrict__ out, int outn) {
    const int o = threadIdx.x;
    if (o < outn) {
        float acc = b_out[o];
        for (int d = 0; d < DIM; ++d)
            acc = fmaf(enc[d], W_out[d * outn + o], acc);
        out[o] = acc;
    }
}

extern "C" void kernel_launch(void* const* d_in, const int* in_sizes, int n_in,
                              void* d_out, int out_size, void* d_ws, size_t ws_size,
                              hipStream_t stream) {
    const int*   x_sym = (const int*)d_in[0];
    // d_in[1] = child_idx (unused: children are 2i+1, 2i+2, invalid when >= N)
    const float* W     = (const float*)d_in[2];
    const float* b     = (const float*)d_in[3];
    const float* W_out = (const float*)d_in[4];
    const float* b_out = (const float*)d_in[5];
    float* out = (float*)d_out;
    float* enc = (float*)d_ws;   // N x DIM fp32 = 16.8 MB

    const int N = in_sizes[0];
    int depth = 0;
    while (((1 << depth) - 1) < N) ++depth;   // 14 for N=16383

    for (int d = depth - 1; d >= 0; --d) {
        int lo = (1 << d) - 1;
        int n = (1 << d);
        if (lo + n > N) n = N - lo;
        if (n >= 256)
            level_big<<<n, 256, 0, stream>>>(x_sym, W, b, enc, lo, N);
        else
            level_small<<<n * 4, 256, 0, stream>>>(x_sym, W, b, enc, lo, N);
    }
    out_kernel<<<1, 64, 0, stream>>>(enc, W_out, b_out, out, out_size);
}